// Round 10
// baseline (195.656 us; speedup 1.0000x reference)
//
#include <hip/hip_runtime.h>

#define DEV __device__ __forceinline__

typedef __attribute__((ext_vector_type(8))) _Float16 h8;
typedef __attribute__((ext_vector_type(4))) float f32x4;
typedef __fp16 __attribute__((ext_vector_type(2))) hh2;

DEV unsigned short f2h(float f) {
  union { _Float16 h[2]; unsigned short u[2]; } v;
  v.h[0] = (_Float16)f;
  return v.u[0];
}

DEV float h2f(unsigned short u) {
  union { _Float16 h[2]; unsigned short u[2]; } v;
  v.u[0] = u;
  return (float)v.h[0];
}

DEV void async_load16(const void* g, void* l) {
  __builtin_amdgcn_global_load_lds(
      (const __attribute__((address_space(1))) void*)g,
      (__attribute__((address_space(3))) void*)l,
      16, 0, 0);
}

// LDS panel XOR swizzle (r8): 1KB chunk = 16 rows x 4 col-blocks (16B).
// Global col-block c of row r stored at slot c ^ ((r>>1)&3); fragment reads use
// qs8 = (quad ^ ((ln>>1)&3))*8. Quarter-wave b128 reads conflict-free.

// ---------------------------------------------------------------- prep: weight casts + rmsnorms
__global__ __launch_bounds__(256) void prep(const float* __restrict__ x,
                                            const float* __restrict__ kv,
                                            const float* __restrict__ wq,
                                            const float* __restrict__ wk,
                                            const float* __restrict__ wv,
                                            const float* __restrict__ wo,
                                            const float* __restrict__ gq,
                                            const float* __restrict__ gkv,
                                            unsigned short* __restrict__ wqb,
                                            unsigned short* __restrict__ wkvb,
                                            unsigned short* __restrict__ wob,
                                            unsigned short* __restrict__ xn,
                                            unsigned short* __restrict__ kvn,
                                            float qscale) {
  const int b = blockIdx.x, tid = threadIdx.x;
  if (b < 2560) {
    const float* src;
    unsigned short* dst;
    float sc = 1.0f;
    int base;
    if (b < 1024) { src = wq; dst = wqb; sc = qscale; base = b; }
    else if (b < 1280) { src = wk; dst = wkvb; base = b - 1024; }
    else if (b < 1536) { src = wv; dst = wkvb + 262144; base = b - 1280; }
    else { src = wo; dst = wob; base = b - 1536; }
    const int i = (base * 256 + tid) * 4;
    float4 v = *(const float4*)&src[i];
    ushort4 o;
    o.x = f2h(v.x * sc); o.y = f2h(v.y * sc);
    o.z = f2h(v.z * sc); o.w = f2h(v.w * sc);
    *(ushort4*)&dst[i] = o;
    return;
  }
  int row = b - 2560;
  const float* src;
  const float* g;
  unsigned short* dst;
  if (row < 4096) { src = x; g = gq; dst = xn; }
  else { row -= 4096; src = kv; g = gkv; dst = kvn; }
  const float* xr = src + (size_t)row * 1024;
  float4 v = *(const float4*)&xr[tid * 4];
  float ss = v.x * v.x + v.y * v.y + v.z * v.z + v.w * v.w;
  ss += __shfl_xor(ss, 32); ss += __shfl_xor(ss, 16);
  ss += __shfl_xor(ss, 8);  ss += __shfl_xor(ss, 4);
  ss += __shfl_xor(ss, 2);  ss += __shfl_xor(ss, 1);
  __shared__ float red[4];
  if ((tid & 63) == 0) red[tid >> 6] = ss;
  __syncthreads();
  float tot = red[0] + red[1] + red[2] + red[3];
  float inv = rsqrtf(tot * (1.0f / 1024.0f) + 1e-5f);
  float4 gv = *(const float4*)&g[tid * 4];
  ushort4 o;
  o.x = f2h(v.x * inv * gv.x); o.y = f2h(v.y * inv * gv.y);
  o.z = f2h(v.z * inv * gv.z); o.w = f2h(v.w * inv * gv.w);
  *(ushort4*)&dst[(size_t)row * 1024 + tid * 4] = o;
}

// ---------------------------------------------------------------- fused q + kv projections
// 128x64 tile, BK=128 (8 iters — halved barrier count), single-buffered,
// swizzled panels, XCD-aware mapping. grid 768 = 3/CU, LDS 48K.
__global__ __launch_bounds__(256) void proj_gemm(const unsigned short* __restrict__ xn,
                                                 const unsigned short* __restrict__ kvn,
                                                 const unsigned short* __restrict__ wqb,
                                                 const unsigned short* __restrict__ wkvb,
                                                 unsigned short* __restrict__ qb,
                                                 unsigned short* __restrict__ kb,
                                                 unsigned short* __restrict__ vTb) {
  __shared__ unsigned short Al[4][128 * 32];
  __shared__ unsigned short Bl[4][64 * 32];
  const int tid = threadIdx.x;
  const int w = tid >> 6, l = tid & 63;
  const int quad = l >> 4, ln = l & 15;
  const int wm0 = (w >> 1) * 64, wn0 = (w & 1) * 32;
  const int r4 = l >> 2;
  const int c4s = (((l & 3) ^ ((l >> 3) & 3))) * 8;
  const int qs8 = (quad ^ ((l >> 1) & 3)) * 8;

  int z = blockIdx.x;
  const unsigned short *A, *W;
  int m0, n0, isq;
  if (z < 512) {
    A = xn; W = wqb; isq = 1;
    m0 = (((z >> 7) << 3) + (z & 7)) * 128;
    n0 = ((z >> 3) & 15) * 64;
  } else {
    z -= 512; A = kvn; W = wkvb; isq = 0;
    m0 = (((z >> 6) << 3) + (z & 7)) * 128;
    n0 = ((z >> 3) & 7) * 64;
  }

  f32x4 acc[4][2] = {};

  for (int it = 0; it < 8; ++it) {
    const int kk = it * 128;
    __syncthreads();
#pragma unroll
    for (int j = 0; j < 12; ++j) {
      const int idx = w * 12 + j;
      if (idx < 32) {
        const int p = idx >> 3, rb = (idx & 7) * 16;
        async_load16(A + (size_t)(m0 + rb + r4) * 1024 + kk + p * 32 + c4s,
                     &Al[p][rb * 32]);
      } else {
        const int ib = idx - 32;
        const int p = ib >> 2, rb = (ib & 3) * 16;
        async_load16(W + (size_t)(n0 + rb + r4) * 1024 + kk + p * 32 + c4s,
                     &Bl[p][rb * 32]);
      }
    }
    __syncthreads();
#pragma unroll
    for (int kc = 0; kc < 4; ++kc) {
      h8 af[4], bf[2];
#pragma unroll
      for (int mi = 0; mi < 4; ++mi)
        af[mi] = *(const h8*)&Al[kc][(wm0 + mi * 16 + ln) * 32 + qs8];
#pragma unroll
      for (int ni = 0; ni < 2; ++ni)
        bf[ni] = *(const h8*)&Bl[kc][(wn0 + ni * 16 + ln) * 32 + qs8];
#pragma unroll
      for (int mi = 0; mi < 4; ++mi)
#pragma unroll
        for (int ni = 0; ni < 2; ++ni)
          acc[mi][ni] = __builtin_amdgcn_mfma_f32_16x16x32_f16(af[mi], bf[ni], acc[mi][ni], 0, 0, 0);
    }
  }

#pragma unroll
  for (int mi = 0; mi < 4; ++mi)
#pragma unroll
    for (int ni = 0; ni < 2; ++ni)
#pragma unroll
      for (int r = 0; r < 4; ++r) {
        const int row = m0 + wm0 + mi * 16 + quad * 4 + r;
        const int col = n0 + wn0 + ni * 16 + ln;
        const unsigned short v = f2h(acc[mi][ni][r]);
        if (isq) {
          qb[((size_t)row << 10) + col] = v;
        } else if (col < 256) {
          kb[(size_t)row * 256 + col] = v;
        } else {
          const int c2 = col - 256, gg = c2 >> 6, dd = c2 & 63;
          const int bb = row >> 11, t = row & 2047;
          vTb[((size_t)((bb * 4 + gg) * 64 + dd) << 11) + t] = v;
        }
      }
}

// ---------------------------------------------------------------- o projection (fused combine) + residual
// BK=128 (8 iters). A-panel = (O0+O1)*inv_l staged via VGPR; W async-DMA.
// LDS 56K -> 2/CU (grid 512 = 2/CU). Swizzled, XCD-mapped.
__global__ __launch_bounds__(256) void o_gemm(const unsigned short* __restrict__ O0,
                                              const unsigned short* __restrict__ O1,
                                              const float* __restrict__ l0p,
                                              const float* __restrict__ l1p,
                                              const unsigned short* __restrict__ wob,
                                              const float* __restrict__ x,
                                              float* __restrict__ out) {
  __shared__ unsigned short Al[4][128 * 32];
  __shared__ unsigned short Bl[4][64 * 32];
  __shared__ float Linv[16 * 128];
  const int tid = threadIdx.x;
  const int w = tid >> 6, l = tid & 63;
  const int quad = l >> 4, ln = l & 15;
  const int wm0 = (w >> 1) * 64, wn0 = (w & 1) * 32;
  const int r4 = l >> 2;
  const int c4s = (((l & 3) ^ ((l >> 3) & 3))) * 8;
  const int qs8 = (quad ^ ((l >> 1) & 3)) * 8;

  const int z = blockIdx.x;
  const int m0 = (((z >> 7) << 3) + (z & 7)) * 128;
  const int n0 = ((z >> 3) & 15) * 64;

  {
    const int h = tid >> 4, r0 = (tid & 15) * 8;
#pragma unroll
    for (int i = 0; i < 8; ++i) {
      const int r = r0 + i;
      const size_t li = (size_t)(m0 + r) * 16 + h;
      Linv[h * 128 + r] = 1.0f / (l0p[li] + l1p[li]);
    }
  }

  const int rowt = tid >> 3;   // 0..31
  const int s0_ = tid & 7;     // base 16B slot (of 16)

  f32x4 acc[4][2] = {};

  for (int it = 0; it < 8; ++it) {
    const int kk = it * 128;
    __syncthreads();
    // B panel via async DMA: 16 chunks / 4 waves
#pragma unroll
    for (int j = 0; j < 4; ++j) {
      const int ib = w * 4 + j;
      const int p = ib >> 2, rb = (ib & 3) * 16;
      async_load16(wob + (size_t)(n0 + rb + r4) * 1024 + kk + p * 32 + c4s,
                   &Bl[p][rb * 32]);
    }
    // A panel via VGPR: sum partials, scale by 1/l, swizzled LDS write
#pragma unroll
    for (int ps = 0; ps < 4; ++ps) {
      const int row = ps * 32 + rowt;
#pragma unroll
      for (int si = 0; si < 2; ++si) {
        const int slot = s0_ + si * 8;          // 0..15
        const int col = kk + slot * 8;
        const int h = col >> 6;
        const size_t gidx = (size_t)(m0 + row) * 1024 + col;
        h8 a0 = *(const h8*)&O0[gidx];
        h8 a1 = *(const h8*)&O1[gidx];
        const _Float16 lv = (_Float16)Linv[h * 128 + row];
        h8 sum = a0 + a1;
#pragma unroll
        for (int q2 = 0; q2 < 8; ++q2) sum[q2] *= lv;
        const int p = slot >> 2, g = slot & 3;
        *(h8*)&Al[p][row * 32 + (g ^ ((row >> 1) & 3)) * 8] = sum;
      }
    }
    __syncthreads();
#pragma unroll
    for (int kc = 0; kc < 4; ++kc) {
      h8 af[4], bf[2];
#pragma unroll
      for (int mi = 0; mi < 4; ++mi)
        af[mi] = *(const h8*)&Al[kc][(wm0 + mi * 16 + ln) * 32 + qs8];
#pragma unroll
      for (int ni = 0; ni < 2; ++ni)
        bf[ni] = *(const h8*)&Bl[kc][(wn0 + ni * 16 + ln) * 32 + qs8];
#pragma unroll
      for (int mi = 0; mi < 4; ++mi)
#pragma unroll
        for (int ni = 0; ni < 2; ++ni)
          acc[mi][ni] = __builtin_amdgcn_mfma_f32_16x16x32_f16(af[mi], bf[ni], acc[mi][ni], 0, 0, 0);
    }
  }

#pragma unroll
  for (int mi = 0; mi < 4; ++mi)
#pragma unroll
    for (int ni = 0; ni < 2; ++ni)
#pragma unroll
      for (int r = 0; r < 4; ++r) {
        const int row = m0 + wm0 + mi * 16 + quad * 4 + r;
        const int col = n0 + wn0 + ni * 16 + ln;
        const size_t idx = ((size_t)row << 10) + col;
        out[idx] = x[idx] + acc[mi][ni][r];
      }
}

// ---------------------------------------------------------------- flash attention (128-T stage, 2 halves)
// grid (16,16,4): s0=bx*128 (4 waves x 32 Q-rows), z = b*2 + T-half.
// Per barrier-pair: stage 128 T of K and V (8 async chunks/wave); compute two
// 64-T halves (QK -> P -> PV). 8 iters instead of 16 -> half the sync points.
// LDS: K 16K + V 16K + P 18K = 50K -> 3 blocks/CU.
__global__ __launch_bounds__(256, 3) void flash_attn(const unsigned short* __restrict__ q,
                                                     const unsigned short* __restrict__ k,
                                                     const unsigned short* __restrict__ vT,
                                                     unsigned short* __restrict__ o0,
                                                     unsigned short* __restrict__ o1,
                                                     float* __restrict__ l0p,
                                                     float* __restrict__ l1p) {
  __shared__ unsigned short Kl[2][128 * 32];  // d-halves, rows t (128), swizzled
  __shared__ unsigned short Vl[4][64 * 32];   // t-quarters (32 each), rows d (64), swizzled
  __shared__ unsigned short P[4 * 32 * 72];   // per-wave 32x64 f16, stride 72

  const int tid = threadIdx.x;
  const int w = tid >> 6, l = tid & 63;
  const int quad = l >> 4, ln = l & 15;
  const int s0 = blockIdx.x * 128;
  const int h = blockIdx.y, g = h >> 2;
  const int b = blockIdx.z >> 1, ts = blockIdx.z & 1;
  const int tbase = ts << 10;

  unsigned short* Opart = ts ? o1 : o0;
  float* lpart = ts ? l1p : l0p;

  h8 qf[2][2];
#pragma unroll
  for (int nq = 0; nq < 2; ++nq)
#pragma unroll
    for (int c = 0; c < 2; ++c)
      qf[nq][c] = *(const h8*)&q[(((size_t)(b * 2048 + s0 + w * 32 + nq * 16 + ln)) << 10) +
                                 h * 64 + c * 32 + quad * 8];

  f32x4 oacc[2][4] = {};
  float lsum[2] = {0.0f, 0.0f};

  const unsigned short* kbase = k + ((size_t)(b * 2048)) * 256 + g * 64;
  const unsigned short* vbase = vT + (((size_t)(b * 4 + g) * 64) << 11);
  unsigned short* Pw = &P[w * 32 * 72];

  const int r4 = l >> 2;
  const int c4s = (((l & 3) ^ ((l >> 3) & 3))) * 8;
  const int qs8 = (quad ^ ((l >> 1) & 3)) * 8;

  const hh2 one2 = {(__fp16)1.0f, (__fp16)1.0f};

  for (int it = 0; it < 8; ++it) {
    const int t0 = tbase + it * 128;
    __syncthreads();
    // stage 128 T: waves 0,1 -> K d-halves (8 chunks each);
    // waves 2,3 -> V t-quarters (2 panels x 4 chunks each)
    if (w < 2) {
#pragma unroll
      for (int c = 0; c < 8; ++c)
        async_load16(kbase + (size_t)(t0 + c * 16 + r4) * 256 + w * 32 + c4s,
                     &Kl[w][c * 512]);
    } else {
#pragma unroll
      for (int c = 0; c < 8; ++c) {
        const int p = (w - 2) * 2 + (c >> 2), cc = c & 3;
        async_load16(vbase + (((size_t)(cc * 16 + r4)) << 11) + t0 + p * 32 + c4s,
                     &Vl[p][cc * 512]);
      }
    }
    __syncthreads();

#pragma unroll
    for (int half = 0; half < 2; ++half) {
      // QK: S^T[t][s] in log2 domain, t within this 64-half
      f32x4 st[2][4];
#pragma unroll
      for (int tb = 0; tb < 4; ++tb) {
        const int trow = half * 64 + tb * 16 + ln;
        h8 ka = *(const h8*)&Kl[0][trow * 32 + qs8];
        h8 kb2 = *(const h8*)&Kl[1][trow * 32 + qs8];
#pragma unroll
        for (int nq = 0; nq < 2; ++nq) {
          f32x4 s = {};
          s = __builtin_amdgcn_mfma_f32_16x16x32_f16(ka, qf[nq][0], s, 0, 0, 0);
          s = __builtin_amdgcn_mfma_f32_16x16x32_f16(kb2, qf[nq][1], s, 0, 0, 0);
          st[nq][tb] = s;
        }
      }

#pragma unroll
      for (int nq = 0; nq < 2; ++nq) {
#pragma unroll
        for (int tb = 0; tb < 4; ++tb) {
          float p0 = __builtin_amdgcn_exp2f(st[nq][tb][0]);
          float p1 = __builtin_amdgcn_exp2f(st[nq][tb][1]);
          float p2 = __builtin_amdgcn_exp2f(st[nq][tb][2]);
          float p3 = __builtin_amdgcn_exp2f(st[nq][tb][3]);
          union { hh2 h2; unsigned int u; } pa, pb;
          pa.h2 = __builtin_amdgcn_cvt_pkrtz(p0, p1);
          pb.h2 = __builtin_amdgcn_cvt_pkrtz(p2, p3);
#if __has_builtin(__builtin_amdgcn_fdot2)
          lsum[nq] = __builtin_amdgcn_fdot2(pa.h2, one2, lsum[nq], false);
          lsum[nq] = __builtin_amdgcn_fdot2(pb.h2, one2, lsum[nq], false);
#else
          lsum[nq] += (p0 + p1) + (p2 + p3);
#endif
          uint2 pk; pk.x = pa.u; pk.y = pb.u;
          *(uint2*)&Pw[(nq * 16 + ln) * 72 + tb * 16 + quad * 4] = pk;
        }
      }

      // wave's own P writes must land before its reads (per-wave region;
      // same-wave DS ops execute in order, so half 1's writes can't pass
      // half 0's reads either)
      asm volatile("s_waitcnt lgkmcnt(0)" ::: "memory");

#pragma unroll
      for (int c = 0; c < 2; ++c) {
        h8 pf0 = *(const h8*)&Pw[(0 * 16 + ln) * 72 + c * 32 + quad * 8];
        h8 pf1 = *(const h8*)&Pw[(1 * 16 + ln) * 72 + c * 32 + quad * 8];
#pragma unroll
        for (int cb = 0; cb < 4; ++cb) {
          h8 vb = *(const h8*)&Vl[half * 2 + c][cb * 512 + ln * 32 + qs8];
          oacc[0][cb] = __builtin_amdgcn_mfma_f32_16x16x32_f16(pf0, vb, oacc[0][cb], 0, 0, 0);
          oacc[1][cb] = __builtin_amdgcn_mfma_f32_16x16x32_f16(pf1, vb, oacc[1][cb], 0, 0, 0);
        }
      }
    }
  }

#pragma unroll
  for (int nq = 0; nq < 2; ++nq) {
    lsum[nq] += __shfl_xor(lsum[nq], 16);
    lsum[nq] += __shfl_xor(lsum[nq], 32);
    if (l < 16)
      lpart[(size_t)(b * 2048 + s0 + w * 32 + nq * 16 + l) * 16 + h] = lsum[nq];
#pragma unroll
    for (int r = 0; r < 4; ++r) {
      const size_t row = (size_t)(b * 2048 + s0 + w * 32 + nq * 16 + quad * 4 + r);
#pragma unroll
      for (int cb = 0; cb < 4; ++cb)
        Opart[(row << 10) + h * 64 + cb * 16 + ln] = f2h(oacc[nq][cb][r]);
    }
  }
}

// ---------------------------------------------------------------- launch
extern "C" void kernel_launch(void* const* d_in, const int* in_sizes, int n_in,
                              void* d_out, int out_size, void* d_ws, size_t ws_size,
                              hipStream_t stream) {
  const float* x   = (const float*)d_in[0];
  const float* kv  = (const float*)d_in[1];
  const float* wq  = (const float*)d_in[2];
  const float* wk  = (const float*)d_in[3];
  const float* wv  = (const float*)d_in[4];
  const float* wo  = (const float*)d_in[5];
  const float* gq  = (const float*)d_in[6];
  const float* gkv = (const float*)d_in[7];

  char* ws = (char*)d_ws;
  unsigned short* xn   = (unsigned short*)(ws);              // 0-8M   xn -> Opart0
  unsigned short* kvn  = (unsigned short*)(ws + 8388608);    // 8-16M  kvn -> Opart1
  unsigned short* qb   = (unsigned short*)(ws + 16777216);   // 16-24M q f16 (pre-scaled)
  unsigned short* kb   = (unsigned short*)(ws + 25165824);   // 24-26M K f16 (4096x256)
  unsigned short* vTb  = (unsigned short*)(ws + 27262976);   // 26-28M V^T f16
  unsigned short* wqb  = (unsigned short*)(ws + 37748736);   // 36-38M wq f16 -> l0p/l1p
  unsigned short* wkvb = (unsigned short*)(ws + 39845888);   // 38-39M [wk;wv] f16
  unsigned short* wob  = (unsigned short*)(ws + 40894464);   // 39-41M wo f16
  unsigned short* Opart0 = xn;
  unsigned short* Opart1 = kvn;
  float* l0p = (float*)wqb;
  float* l1p = (float*)(ws + 37748736 + 262144);

  const float qscale = 0.18033688011112042f;  // (1/8) * log2(e)

  prep<<<10752, 256, 0, stream>>>(x, kv, wq, wk, wv, wo, gq, gkv,
                                  wqb, wkvb, wob, xn, kvn, qscale);

  // fused q + kv projections (BK=128, swizzled, XCD-mapped)
  proj_gemm<<<768, 256, 0, stream>>>(xn, kvn, wqb, wkvb, qb, kb, vTb);

  // flash: 128 Q-rows/block, T-split 2, 128-T stages -> 1024 blocks (3/CU)
  flash_attn<<<dim3(16, 16, 4), 256, 0, stream>>>(qb, kb, vTb, Opart0, Opart1, l0p, l1p);

  // o projection with fused T-split combine + residual (BK=128)
  o_gemm<<<512, 256, 0, stream>>>(Opart0, Opart1, l0p, l1p, wob, x, (float*)d_out);
}